// Round 8
// baseline (117.628 us; speedup 1.0000x reference)
//
#include <hip/hip_runtime.h>

typedef float v2f __attribute__((ext_vector_type(2)));

#define K_CW 256
#define PPT 4       // points per thread (2 packed pairs)
#define NQ 4        // split-K quarters
#define KQ (K_CW / NQ)  // 64 k per quarter

// Packed codebook entry: 16 floats (64 B), values DUPLICATED for packed ops:
// {m0,m0, m1,m1, m2,m2, m3,m3, cs,cs, 0x6}  where m_i = -2*c_i (exact scaling),
// cs = numpy-rounded ||c||^2: ((c0*c0 + c1*c1) + c2*c2) + c3*c3
__global__ void vq_pack_kernel(const float* __restrict__ tlut, float* __restrict__ pk) {
    int k = threadIdx.x;  // 256 threads, 1 block
    float c0 = tlut[k * 4 + 0];
    float c1 = tlut[k * 4 + 1];
    float c2 = tlut[k * 4 + 2];
    float c3 = tlut[k * 4 + 3];
    float cs = __fadd_rn(__fadd_rn(__fadd_rn(__fmul_rn(c0, c0), __fmul_rn(c1, c1)),
                                   __fmul_rn(c2, c2)),
                         __fmul_rn(c3, c3));
    float* b = pk + k * 16;
    b[0] = -2.0f * c0; b[1] = b[0];
    b[2] = -2.0f * c1; b[3] = b[2];
    b[4] = -2.0f * c2; b[5] = b[4];
    b[6] = -2.0f * c3; b[7] = b[6];
    b[8] = cs;         b[9] = cs;
    b[10] = 0.f; b[11] = 0.f; b[12] = 0.f; b[13] = 0.f; b[14] = 0.f; b[15] = 0.f;
}

__global__ __launch_bounds__(1024, 8) void vq_argmin_kernel(
    const float* __restrict__ X,
    const float* __restrict__ tlut,
    const float* __restrict__ pk,
    float* __restrict__ outX,   // [B,4] reconstruction
    float* __restrict__ outS,   // [B] state, stored as float
    int B) {
    // split-K x4 (R7 skeleton) + packed-fp32 math: two POINTS per v2f register
    // pair, so each v_pk_{mul,fma,add}_f32 does both points' chains at once.
    // Per-component rounding is IEEE-identical to the scalar chain:
    //   acc = ((x0*m0) fma x1*m1 fma x2*m2 fma x3*m3), m_i = -2c_i (exact x2)
    //   => acc == -2*cross bit-exactly; d = (acc + xsq) + cs == reference.
    __shared__ float4 sd[3 * 256];  // quarters 1..3 bestd
    __shared__ int4   si[3 * 256];  // quarters 1..3 besti

    const int t = threadIdx.x;
    const int tt = t & 255;
    const int q = t >> 8;  // wave-uniform (wave = 64 consecutive threads)
    const int kbase = __builtin_amdgcn_readfirstlane(q << 6);

    const int g = blockIdx.x * 256 + tt;   // point-group id
    const int stride = B / PPT;            // strided points -> coalesced

    const float4* __restrict__ X4 = reinterpret_cast<const float4*>(X);
    const float4* __restrict__ T4 = reinterpret_cast<const float4*>(tlut);
    const v2f* __restrict__ PKv = reinterpret_cast<const v2f*>(pk);  // 8 v2f per entry

    // load 4 points (coalesced float4), pack pairs {pt0,pt1} and {pt2,pt3}
    float4 xv[PPT];
    float xsq[PPT];
    #pragma unroll
    for (int i = 0; i < PPT; ++i) {
        xv[i] = X4[g + i * stride];
        // x_sq with numpy rounding: sequential adds of rounded squares
        xsq[i] = __fadd_rn(__fadd_rn(__fadd_rn(__fmul_rn(xv[i].x, xv[i].x),
                                               __fmul_rn(xv[i].y, xv[i].y)),
                                     __fmul_rn(xv[i].z, xv[i].z)),
                           __fmul_rn(xv[i].w, xv[i].w));
    }
    v2f px0[2], px1[2], px2[2], px3[2], pxs[2];
    #pragma unroll
    for (int pp = 0; pp < 2; ++pp) {
        px0[pp] = (v2f){xv[2 * pp].x, xv[2 * pp + 1].x};
        px1[pp] = (v2f){xv[2 * pp].y, xv[2 * pp + 1].y};
        px2[pp] = (v2f){xv[2 * pp].z, xv[2 * pp + 1].z};
        px3[pp] = (v2f){xv[2 * pp].w, xv[2 * pp + 1].w};
        pxs[pp] = (v2f){xsq[2 * pp], xsq[2 * pp + 1]};
    }

    float bestd[PPT];
    int besti[PPT];
    #pragma unroll
    for (int i = 0; i < PPT; ++i) { bestd[i] = __builtin_inff(); besti[i] = kbase; }

    #pragma unroll 8
    for (int kk = 0; kk < KQ; ++kk) {
        const int k = kbase + kk;                    // wave-uniform -> s_load path
        const v2f* eb = PKv + (size_t)k * 8;
        const v2f m0 = eb[0], m1 = eb[1], m2 = eb[2], m3 = eb[3], cs = eb[4];
        #pragma unroll
        for (int pp = 0; pp < 2; ++pp) {
            v2f acc = m0 * px0[pp];                               // v_pk_mul_f32
            acc = __builtin_elementwise_fma(m1, px1[pp], acc);    // v_pk_fma_f32
            acc = __builtin_elementwise_fma(m2, px2[pp], acc);
            acc = __builtin_elementwise_fma(m3, px3[pp], acc);
            acc = acc + pxs[pp];                                  // v_pk_add_f32
            v2f d = acc + cs;                                     // v_pk_add_f32
            const int iA = 2 * pp, iB = 2 * pp + 1;
            // argmin, first occurrence (strict <), ascending k (per point, scalar)
            besti[iA] = (d.x < bestd[iA]) ? k : besti[iA];
            bestd[iA] = fminf(d.x, bestd[iA]);
            besti[iB] = (d.y < bestd[iB]) ? k : besti[iB];
            bestd[iB] = fminf(d.y, bestd[iB]);
        }
    }

    if (q > 0) {
        sd[(q - 1) * 256 + tt] = make_float4(bestd[0], bestd[1], bestd[2], bestd[3]);
        si[(q - 1) * 256 + tt] = make_int4(besti[0], besti[1], besti[2], besti[3]);
    }
    __syncthreads();
    if (q == 0) {
        // merge quarters ascending in k; strict '<' -> smaller k wins ties
        // (np.argmin first-occurrence)
        #pragma unroll
        for (int j = 0; j < 3; ++j) {
            const float4 od = sd[j * 256 + tt];
            const int4   oi = si[j * 256 + tt];
            if (od.x < bestd[0]) { bestd[0] = od.x; besti[0] = oi.x; }
            if (od.y < bestd[1]) { bestd[1] = od.y; besti[1] = oi.y; }
            if (od.z < bestd[2]) { bestd[2] = od.z; besti[2] = oi.z; }
            if (od.w < bestd[3]) { bestd[3] = od.w; besti[3] = oi.w; }
        }
        #pragma unroll
        for (int i = 0; i < PPT; ++i) {
            const int p = g + i * stride;
            reinterpret_cast<float4*>(outX)[p] = T4[besti[i]];
            outS[p] = (float)besti[i];
        }
    }
}

extern "C" void kernel_launch(void* const* d_in, const int* in_sizes, int n_in,
                              void* d_out, int out_size, void* d_ws, size_t ws_size,
                              hipStream_t stream) {
    const float* X    = (const float*)d_in[0];   // [B,4]
    const float* tlut = (const float*)d_in[1];   // [256,4]
    const int B = in_sizes[0] / 4;

    float* outX = (float*)d_out;          // first B*4 floats: hatX
    float* outS = outX + (size_t)B * 4;   // next B floats: state (as float)

    float* pk = (float*)d_ws;             // 256*16 floats packed dup codebook (16 KB)

    vq_pack_kernel<<<1, 256, 0, stream>>>(tlut, pk);

    const int groups = B / PPT;           // 262144 point-groups
    const int grid = groups / 256;        // 1024 blocks of 1024 threads
    vq_argmin_kernel<<<grid, 1024, 0, stream>>>(X, tlut, pk, outX, outS, B);
}